// Round 7
// baseline (310.027 us; speedup 1.0000x reference)
//
#include <hip/hip_runtime.h>
#include <stdint.h>

#define C_IN 64
#define C_OUT 128
#define NBUCK 65536
#define TPTS 128  // points per k6 tile

typedef unsigned int u32;
typedef unsigned long long u64;

// ---------- K0: zero the bucket histogram ----------
__global__ void k0_zero(uint4* __restrict__ hist4) {
  int i = blockIdx.x * blockDim.x + threadIdx.x;
  hist4[i] = make_uint4(0u, 0u, 0u, 0u);
}

// ---------- K1: compute compressed keys + bucket histogram ----------
__global__ void k1_keys(const int* __restrict__ grid, const int* __restrict__ batch,
                        const int* __restrict__ stride, int n,
                        u32* __restrict__ keys, u32* __restrict__ hist) {
  int i = blockIdx.x * blockDim.x + threadIdx.x;
  if (i >= n) return;
  int s = stride[0];
  u32 gx, gy, gz;
  if (s == 2) {  // common case: shift instead of 3 int divides
    gx = ((u32)grid[3 * i]) >> 1;
    gy = ((u32)grid[3 * i + 1]) >> 1;
    gz = ((u32)grid[3 * i + 2]) >> 1;
  } else {
    gx = (u32)(grid[3 * i] / s);
    gy = (u32)(grid[3 * i + 1] / s);
    gz = (u32)(grid[3 * i + 2] / s);
  }
  u32 b = (u32)batch[i];
  u32 key = (b << 30) | (gz << 20) | (gy << 10) | gx;
  keys[i] = key;
  atomicAdd(&hist[key >> 16], 1u);
}

// ---------- K2: exclusive scan of 65536 bucket counts (1 block) ----------
__global__ void k2_scan(const u32* __restrict__ hist, u32* __restrict__ off,
                        u32* __restrict__ cursor) {
  __shared__ u32 part[1024];
  int t = threadIdx.x;
  u32 s = 0;
  for (int k = 0; k < 64; k++) s += hist[t * 64 + k];
  part[t] = s;
  __syncthreads();
  for (int d = 1; d < 1024; d <<= 1) {
    u32 v = (t >= d) ? part[t - d] : 0u;
    __syncthreads();
    part[t] += v;
    __syncthreads();
  }
  u32 run = part[t] - s;
  for (int k = 0; k < 64; k++) {
    u32 h = hist[t * 64 + k];
    off[t * 64 + k] = run;
    cursor[t * 64 + k] = run;
    run += h;
  }
  if (t == 1023) off[NBUCK] = run;  // == n
}

// ---------- K3: scatter (key,idx) pairs into buckets ----------
__global__ void k3_scatter(const u32* __restrict__ keys, u32* __restrict__ cursor,
                           u64* __restrict__ pairs, int n) {
  int i = blockIdx.x * blockDim.x + threadIdx.x;
  if (i >= n) return;
  u32 key = keys[i];
  u32 pos = atomicAdd(&cursor[key >> 16], 1u);
  pairs[pos] = ((u64)key << 32) | (u32)i;
}

// ---------- K4: per-bucket rank sort + unique-key count, one WAVE per bucket ----------
__global__ __launch_bounds__(256) void k4_sort(u64* __restrict__ pairs,
                                               const u32* __restrict__ off,
                                               u32* __restrict__ bucketHeads) {
  int b = (blockIdx.x * blockDim.x + threadIdx.x) >> 6;
  int lane = threadIdx.x & 63;
  if (b >= NBUCK) return;
  u32 lo = off[b], hi = off[b + 1];
  u32 k = hi - lo;
  if (k == 0) { if (lane == 0) bucketHeads[b] = 0u; return; }
  if (k == 1) { if (lane == 0) bucketHeads[b] = 1u; return; }
  if (k <= 64) {
    u64 v = (lane < (int)k) ? pairs[lo + lane] : ~0ull;
    u32 mykey = (u32)(v >> 32);
    int rank = 0, same_smaller = 0;
    for (u32 j = 0; j < k; j++) {
      u64 o = __shfl(v, (int)j, 64);
      bool lt = o < v;
      rank += lt ? 1 : 0;
      same_smaller += (lt && ((u32)(o >> 32) == mykey)) ? 1 : 0;
    }
    bool head = (lane < (int)k) && (same_smaller == 0);
    u64 hb = __ballot(head);
    if (lane < (int)k) pairs[lo + rank] = v;  // all loads done before any store
    if (lane == 0) bucketHeads[b] = (u32)__popcll(hb);
  } else if (lane == 0) {  // cold fallback, statistically never taken
    for (u32 i = lo + 1; i < hi; i++) {
      u64 v = pairs[i];
      u32 j = i;
      while (j > lo && pairs[j - 1] > v) { pairs[j] = pairs[j - 1]; j--; }
      pairs[j] = v;
    }
    u32 u = 1;
    for (u32 i = lo + 1; i < hi; i++)
      u += ((u32)(pairs[i] >> 32) != (u32)(pairs[i - 1] >> 32)) ? 1u : 0u;
    bucketHeads[b] = u;
  }
}

// ---------- K2b: exclusive scan of bucket head counts -> segment bases ----------
__global__ void k2b_scan(const u32* __restrict__ bucketHeads, u32* __restrict__ segBase,
                         u32* __restrict__ meta, u32* __restrict__ segStart, int n) {
  __shared__ u32 part[1024];
  int t = threadIdx.x;
  u32 s = 0;
  for (int k = 0; k < 64; k++) s += bucketHeads[t * 64 + k];
  part[t] = s;
  __syncthreads();
  for (int d = 1; d < 1024; d <<= 1) {
    u32 v = (t >= d) ? part[t - d] : 0u;
    __syncthreads();
    part[t] += v;
    __syncthreads();
  }
  u32 run = part[t] - s;
  for (int k = 0; k < 64; k++) {
    segBase[t * 64 + k] = run;
    run += bucketHeads[t * 64 + k];
  }
  if (t == 1023) {
    segBase[NBUCK] = run;
    meta[0] = run;            // numSeg
    meta[1] = 0u;             // multi-cluster counter
    segStart[run] = (u32)n;   // sentinel
  }
}

// ---------- K5: wave-per-bucket assignment + counts + coord means ----------
__global__ __launch_bounds__(256) void k5_assign(
    const u64* __restrict__ pairs, const u32* __restrict__ off,
    const u32* __restrict__ segBase, const float* __restrict__ coord,
    u32* __restrict__ segStart, u32* __restrict__ cluster,
    float* __restrict__ out_grid, float* __restrict__ out_batch,
    float* __restrict__ out_coord, float* __restrict__ out_counts,
    u32* __restrict__ meta, u32* __restrict__ multiList) {
  int b = (blockIdx.x * blockDim.x + threadIdx.x) >> 6;
  int lane = threadIdx.x & 63;
  if (b >= NBUCK) return;
  u32 lo = off[b], hi = off[b + 1];
  u32 k = hi - lo;
  if (k == 0) return;
  if (k <= 64) {
    bool inb = lane < (int)k;
    u64 v = inb ? pairs[lo + lane] : ~0ull;
    u32 mykey = (u32)(v >> 32);
    u32 idx = (u32)(v & 0xFFFFFFFFu);
    float cx = 0.f, cy = 0.f, cz = 0.f;
    if (inb) {
      cx = coord[(size_t)idx * 3 + 0];
      cy = coord[(size_t)idx * 3 + 1];
      cz = coord[(size_t)idx * 3 + 2];
    }
    u64 pv = __shfl_up(v, 1, 64);
    bool head = inb && (lane == 0 || (u32)(pv >> 32) != mykey);
    u64 hb = __ballot(head);
    u64 above = (lane < 63) ? (hb >> (lane + 1)) : 0ull;
    // segmented suffix-sum: head lane accumulates its whole run
#pragma unroll
    for (int d = 1; d < 64; d <<= 1) {
      float ox = __shfl_down(cx, d, 64);
      float oy = __shfl_down(cy, d, 64);
      float oz = __shfl_down(cz, d, 64);
      bool ok = (lane + d < 64) && ((above & ((d < 64 ? (1ull << d) : 0ull) - 1ull)) == 0ull);
      if (ok) { cx += ox; cy += oy; cz += oz; }
    }
    if (inb) {
      u32 seg = segBase[b] + (u32)__popcll(hb << (63 - lane)) - 1u;
      u32 cnt = above ? (u32)__builtin_ctzll(above) + 1u : (k - (u32)lane);
      bool multi_run = head ? (cnt > 1u) : true;  // non-head => run len > 1
      cluster[idx] = seg | (multi_run ? 0x80000000u : 0u);
      if (head) {
        segStart[seg] = lo + (u32)lane;
        out_grid[(size_t)seg * 3 + 0] = (float)(mykey & 0x3FFu);
        out_grid[(size_t)seg * 3 + 1] = (float)((mykey >> 10) & 0x3FFu);
        out_grid[(size_t)seg * 3 + 2] = (float)((mykey >> 20) & 0x3FFu);
        out_batch[seg] = (float)(mykey >> 30);
        float fc = (float)cnt;
        out_counts[seg] = fc;
        out_coord[(size_t)seg * 3 + 0] = cx / fc;
        out_coord[(size_t)seg * 3 + 1] = cy / fc;
        out_coord[(size_t)seg * 3 + 2] = cz / fc;
        if (cnt > 1u) {
          u32 slot = atomicAdd(&meta[1], 1u);
          multiList[slot] = seg;
        }
      }
    }
  } else if (lane == 0) {  // cold fallback, statistically never taken
    u32 seg = segBase[b];
    u32 p = lo;
    while (p < hi) {
      u32 kk = (u32)(pairs[p] >> 32);
      u32 q = p;
      float sx = 0.f, sy = 0.f, sz = 0.f;
      while (q < hi && (u32)(pairs[q] >> 32) == kk) {
        u32 idx = (u32)(pairs[q] & 0xFFFFFFFFu);
        sx += coord[(size_t)idx * 3 + 0];
        sy += coord[(size_t)idx * 3 + 1];
        sz += coord[(size_t)idx * 3 + 2];
        q++;
      }
      u32 cnt = q - p;
      u32 multi = (cnt > 1u) ? 0x80000000u : 0u;
      for (u32 e = p; e < q; e++) cluster[(u32)(pairs[e] & 0xFFFFFFFFu)] = seg | multi;
      segStart[seg] = p;
      out_grid[(size_t)seg * 3 + 0] = (float)(kk & 0x3FFu);
      out_grid[(size_t)seg * 3 + 1] = (float)((kk >> 10) & 0x3FFu);
      out_grid[(size_t)seg * 3 + 2] = (float)((kk >> 20) & 0x3FFu);
      out_batch[seg] = (float)(kk >> 30);
      float fc = (float)cnt;
      out_counts[seg] = fc;
      out_coord[(size_t)seg * 3 + 0] = sx / fc;
      out_coord[(size_t)seg * 3 + 1] = sy / fc;
      out_coord[(size_t)seg * 3 + 2] = sz / fc;
      if (cnt > 1u) {
        u32 slot = atomicAdd(&meta[1], 1u);
        multiList[slot] = seg;
      }
      seg++;
      p = q;
    }
  }
}

// ---------- K6: register-tiled GEMM (128 pts x 128 ch per block) + scatter ----------
__global__ __launch_bounds__(256) void k6_gemm(
    const float* __restrict__ feat, const float* __restrict__ weight,
    const float* __restrict__ bias, const u32* __restrict__ cluster,
    float* __restrict__ out_feat, int n) {
  __shared__ float fl[C_IN * TPTS];   // 32 KB  [k][p]
  __shared__ float wl[C_IN * C_OUT];  // 32 KB  [k][c]
  __shared__ u32 ldsC[TPTS];
  const int tid = threadIdx.x;
  const int cg = tid & 15;   // channel group: channels cg*8 .. +7
  const int pg = tid >> 4;   // point group:   points  pg*8 .. +7

  {
    int c = tid >> 1;
    int kh = (tid & 1) * 32;
    const float4* src = (const float4*)(weight + (size_t)c * C_IN + kh);
#pragma unroll
    for (int q = 0; q < 8; q++) {
      float4 v = src[q];
      int k = kh + q * 4;
      wl[(k + 0) * C_OUT + c] = v.x;
      wl[(k + 1) * C_OUT + c] = v.y;
      wl[(k + 2) * C_OUT + c] = v.z;
      wl[(k + 3) * C_OUT + c] = v.w;
    }
  }
  float breg[8];
#pragma unroll
  for (int j = 0; j < 8; j++) breg[j] = bias[cg * 8 + j];

  const int ntile = (n + TPTS - 1) / TPTS;
  for (int t = blockIdx.x; t < ntile; t += gridDim.x) {
    const int base = t * TPTS;
    __syncthreads();
    {
      int p = tid >> 1;
      int kh = (tid & 1) * 32;
      int gp = base + p;
      if (gp < n) {
        const float4* src = (const float4*)(feat + (size_t)gp * C_IN + kh);
#pragma unroll
        for (int q = 0; q < 8; q++) {
          float4 v = src[q];
          int k = kh + q * 4;
          fl[(k + 0) * TPTS + p] = v.x;
          fl[(k + 1) * TPTS + p] = v.y;
          fl[(k + 2) * TPTS + p] = v.z;
          fl[(k + 3) * TPTS + p] = v.w;
        }
      } else {
#pragma unroll
        for (int q = 0; q < 32; q++) fl[(kh + q) * TPTS + p] = 0.f;
      }
      if (tid < TPTS) ldsC[tid] = (base + tid < n) ? cluster[base + tid] : 0x80000000u;
    }
    __syncthreads();

    float acc[8][8];
#pragma unroll
    for (int i = 0; i < 8; i++)
#pragma unroll
      for (int j = 0; j < 8; j++) acc[i][j] = 0.f;

#pragma unroll 2
    for (int k = 0; k < C_IN; k++) {
      float4 f0 = *(const float4*)(fl + k * TPTS + pg * 8);
      float4 f1 = *(const float4*)(fl + k * TPTS + pg * 8 + 4);
      float4 w0 = *(const float4*)(wl + k * C_OUT + cg * 8);
      float4 w1 = *(const float4*)(wl + k * C_OUT + cg * 8 + 4);
      float fv[8] = {f0.x, f0.y, f0.z, f0.w, f1.x, f1.y, f1.z, f1.w};
      float wv[8] = {w0.x, w0.y, w0.z, w0.w, w1.x, w1.y, w1.z, w1.w};
#pragma unroll
      for (int i = 0; i < 8; i++)
#pragma unroll
        for (int j = 0; j < 8; j++) acc[i][j] = fmaf(fv[i], wv[j], acc[i][j]);
    }

#pragma unroll
    for (int i = 0; i < 8; i++) {
      int p = pg * 8 + i;
      u32 cl = ldsC[p];
      if (cl & 0x80000000u) continue;  // multi-point (k8) or tail
      float4 o0 = {acc[i][0] + breg[0], acc[i][1] + breg[1],
                   acc[i][2] + breg[2], acc[i][3] + breg[3]};
      float4 o1 = {acc[i][4] + breg[4], acc[i][5] + breg[5],
                   acc[i][6] + breg[6], acc[i][7] + breg[7]};
      float4* dst = (float4*)(out_feat + (size_t)cl * C_OUT + cg * 8);
      dst[0] = o0;
      dst[1] = o1;
    }
  }
}

// ---------- K7t: zero the invalid tail rows ----------
__global__ void k7_tail(const u32* __restrict__ meta, float* __restrict__ out_feat,
                        float* __restrict__ out_coord, float* __restrict__ out_grid,
                        float* __restrict__ out_batch, float* __restrict__ out_counts, int n) {
  int t = blockIdx.x * blockDim.x + threadIdx.x;
  if (t >= n) return;
  if ((u32)t < meta[0]) return;  // valid segment: fully written by k5/k6/k8
  out_counts[t] = 0.f;
  out_batch[t] = 0.f;
  out_coord[(size_t)t * 3 + 0] = 0.f;
  out_coord[(size_t)t * 3 + 1] = 0.f;
  out_coord[(size_t)t * 3 + 2] = 0.f;
  out_grid[(size_t)t * 3 + 0] = 0.f;
  out_grid[(size_t)t * 3 + 1] = 0.f;
  out_grid[(size_t)t * 3 + 2] = 0.f;
  float4 z = {0.f, 0.f, 0.f, 0.f};
  float4* row = (float4*)(out_feat + (size_t)t * C_OUT);
#pragma unroll
  for (int q = 0; q < 32; q++) row[q] = z;
}

// ---------- K8: multi-point clusters — parallel matmul + max (1 block/cluster) ----------
__global__ __launch_bounds__(128) void k8_multi(
    const u64* __restrict__ pairs, const u32* __restrict__ segStart,
    const u32* __restrict__ meta, const u32* __restrict__ multiList,
    const float* __restrict__ feat, const float* __restrict__ weight,
    const float* __restrict__ bias, float* __restrict__ out_feat) {
  __shared__ float ldsF[C_IN];
  const int c = threadIdx.x;
  float wreg[C_IN];
  const float4* wrow = (const float4*)(weight + (size_t)c * C_IN);
#pragma unroll
  for (int q = 0; q < 16; q++) {
    float4 v = wrow[q];
    wreg[4 * q] = v.x; wreg[4 * q + 1] = v.y; wreg[4 * q + 2] = v.z; wreg[4 * q + 3] = v.w;
  }
  const float bc = bias[c];
  const u32 nm = meta[1];
  for (u32 m = blockIdx.x; m < nm; m += gridDim.x) {
    u32 seg = multiList[m];
    u32 st = segStart[seg], en = segStart[seg + 1];
    float mx = -3.4e38f;
    for (u32 e = st; e < en; e++) {
      u32 idx = (u32)(pairs[e] & 0xFFFFFFFFu);
      __syncthreads();
      if (c < 16) ((float4*)ldsF)[c] = ((const float4*)(feat + (size_t)idx * C_IN))[c];
      __syncthreads();
      float d = bc;
#pragma unroll
      for (int q = 0; q < 16; q++) {
        float4 v = ((const float4*)ldsF)[q];
        d = fmaf(v.x, wreg[4 * q], d);
        d = fmaf(v.y, wreg[4 * q + 1], d);
        d = fmaf(v.z, wreg[4 * q + 2], d);
        d = fmaf(v.w, wreg[4 * q + 3], d);
      }
      mx = fmaxf(mx, d);
    }
    out_feat[(size_t)seg * C_OUT + c] = mx;
  }
}

extern "C" void kernel_launch(void* const* d_in, const int* in_sizes, int n_in,
                              void* d_out, int out_size, void* d_ws, size_t ws_size,
                              hipStream_t stream) {
  const float* feat = (const float*)d_in[0];
  const float* coord = (const float*)d_in[1];
  const float* weight = (const float*)d_in[2];
  const float* bias = (const float*)d_in[3];
  const int* grid = (const int*)d_in[4];
  const int* batch = (const int*)d_in[5];
  const int* stride = (const int*)d_in[6];
  const int n = in_sizes[0] / C_IN;

  float* out_feat = (float*)d_out;
  float* out_coord = out_feat + (size_t)n * C_OUT;
  float* out_grid = out_coord + (size_t)n * 3;
  float* out_batch = out_grid + (size_t)n * 3;
  float* out_counts = out_batch + n;

  u32* W = (u32*)d_ws;
  u32* hist = W;                     // 65536
  u32* cursor = W + 65536;           // 65536 (reused as bucketHeads after k3)
  u32* off = W + 131072;             // 65537
  u32* segBase = W + 196864;         // 65537
  u32* meta = W + 262464;            // [0]=numSeg [1]=numMulti
  u32* multiList = W + 262528;       // 65536
  u32* keys = W + 328192;            // n
  u32* cluster = keys + n;           // n
  u32* segStart = cluster + n;       // n+1
  size_t pe = 328192 + 3 * (size_t)n + 2;
  pe &= ~(size_t)1;                  // 8-byte align for u64
  u64* pairs = (u64*)(W + pe);       // n
  u32* bucketHeads = cursor;         // alias: cursor is dead after k3

  int nb = (n + 255) / 256;
  k0_zero<<<NBUCK / 4 / 256, 256, 0, stream>>>((uint4*)hist);
  k1_keys<<<nb, 256, 0, stream>>>(grid, batch, stride, n, keys, hist);
  k2_scan<<<1, 1024, 0, stream>>>(hist, off, cursor);
  k3_scatter<<<nb, 256, 0, stream>>>(keys, cursor, pairs, n);
  k4_sort<<<NBUCK / 4, 256, 0, stream>>>(pairs, off, bucketHeads);
  k2b_scan<<<1, 1024, 0, stream>>>(bucketHeads, segBase, meta, segStart, n);
  k5_assign<<<NBUCK / 4, 256, 0, stream>>>(pairs, off, segBase, coord, segStart, cluster,
                                           out_grid, out_batch, out_coord, out_counts,
                                           meta, multiList);
  k6_gemm<<<2048, 256, 0, stream>>>(feat, weight, bias, cluster, out_feat, n);
  k7_tail<<<nb, 256, 0, stream>>>(meta, out_feat, out_coord, out_grid, out_batch, out_counts, n);
  k8_multi<<<256, 128, 0, stream>>>(pairs, segStart, meta, multiList, feat, weight, bias, out_feat);
}

// Round 8
// 271.643 us; speedup vs baseline: 1.1413x; 1.1413x over previous
//
#include <hip/hip_runtime.h>
#include <stdint.h>

#define C_IN 64
#define C_OUT 128
#define NBUCK 65536

typedef unsigned int u32;
typedef unsigned long long u64;
typedef __attribute__((ext_vector_type(8))) short bf16x8;
typedef __attribute__((ext_vector_type(4))) float f32x4;

__device__ __forceinline__ unsigned short f2bf(float f) {
  u32 x = __float_as_uint(f);
  u32 r = x + 0x7FFFu + ((x >> 16) & 1u);  // round-to-nearest-even
  return (unsigned short)(r >> 16);
}
__device__ __forceinline__ bf16x8 cvt8(float4 a, float4 b) {
  bf16x8 r;
  r[0] = (short)f2bf(a.x); r[1] = (short)f2bf(a.y);
  r[2] = (short)f2bf(a.z); r[3] = (short)f2bf(a.w);
  r[4] = (short)f2bf(b.x); r[5] = (short)f2bf(b.y);
  r[6] = (short)f2bf(b.z); r[7] = (short)f2bf(b.w);
  return r;
}

// ---------- K0: zero the bucket histogram ----------
__global__ void k0_zero(uint4* __restrict__ hist4) {
  int i = blockIdx.x * blockDim.x + threadIdx.x;
  hist4[i] = make_uint4(0u, 0u, 0u, 0u);
}

// ---------- K1: compute compressed keys + bucket histogram ----------
__global__ void k1_keys(const int* __restrict__ grid, const int* __restrict__ batch,
                        const int* __restrict__ stride, int n,
                        u32* __restrict__ keys, u32* __restrict__ hist) {
  int i = blockIdx.x * blockDim.x + threadIdx.x;
  if (i >= n) return;
  int s = stride[0];
  u32 gx, gy, gz;
  if (s == 2) {
    gx = ((u32)grid[3 * i]) >> 1;
    gy = ((u32)grid[3 * i + 1]) >> 1;
    gz = ((u32)grid[3 * i + 2]) >> 1;
  } else {
    gx = (u32)(grid[3 * i] / s);
    gy = (u32)(grid[3 * i + 1] / s);
    gz = (u32)(grid[3 * i + 2] / s);
  }
  u32 b = (u32)batch[i];
  u32 key = (b << 30) | (gz << 20) | (gy << 10) | gx;
  keys[i] = key;
  atomicAdd(&hist[key >> 16], 1u);
}

// ---------- K2: exclusive scan of 65536 bucket counts (1 block, uint4 I/O) ----------
__global__ void k2_scan(const u32* __restrict__ hist, u32* __restrict__ off,
                        u32* __restrict__ cursor) {
  __shared__ u32 part[1024];
  int t = threadIdx.x;
  const uint4* h4 = (const uint4*)hist;
  uint4 v[16];
  u32 s = 0;
#pragma unroll
  for (int q = 0; q < 16; q++) {
    v[q] = h4[t * 16 + q];
    s += v[q].x + v[q].y + v[q].z + v[q].w;
  }
  part[t] = s;
  __syncthreads();
  for (int d = 1; d < 1024; d <<= 1) {
    u32 x = (t >= d) ? part[t - d] : 0u;
    __syncthreads();
    part[t] += x;
    __syncthreads();
  }
  u32 run = part[t] - s;
  uint4* off4 = (uint4*)off;
  uint4* cur4 = (uint4*)cursor;
#pragma unroll
  for (int q = 0; q < 16; q++) {
    uint4 o;
    o.x = run; run += v[q].x;
    o.y = run; run += v[q].y;
    o.z = run; run += v[q].z;
    o.w = run; run += v[q].w;
    off4[t * 16 + q] = o;
    cur4[t * 16 + q] = o;
  }
  if (t == 1023) off[NBUCK] = run;  // == n
}

// ---------- K3: scatter (key,idx) pairs into buckets ----------
__global__ void k3_scatter(const u32* __restrict__ keys, u32* __restrict__ cursor,
                           u64* __restrict__ pairs, int n) {
  int i = blockIdx.x * blockDim.x + threadIdx.x;
  if (i >= n) return;
  u32 key = keys[i];
  u32 pos = atomicAdd(&cursor[key >> 16], 1u);
  pairs[pos] = ((u64)key << 32) | (u32)i;
}

// ---------- K4: per-bucket rank sort + unique-key count, one WAVE per bucket ----------
__global__ __launch_bounds__(256) void k4_sort(u64* __restrict__ pairs,
                                               const u32* __restrict__ off,
                                               u32* __restrict__ bucketHeads) {
  int b = (blockIdx.x * blockDim.x + threadIdx.x) >> 6;
  int lane = threadIdx.x & 63;
  if (b >= NBUCK) return;
  u32 lo = off[b], hi = off[b + 1];
  u32 k = hi - lo;
  if (k == 0) { if (lane == 0) bucketHeads[b] = 0u; return; }
  if (k == 1) { if (lane == 0) bucketHeads[b] = 1u; return; }
  if (k <= 64) {
    u64 v = (lane < (int)k) ? pairs[lo + lane] : ~0ull;
    u32 mykey = (u32)(v >> 32);
    int rank = 0, same_smaller = 0;
    for (u32 j = 0; j < k; j++) {
      u64 o = __shfl(v, (int)j, 64);
      bool lt = o < v;
      rank += lt ? 1 : 0;
      same_smaller += (lt && ((u32)(o >> 32) == mykey)) ? 1 : 0;
    }
    bool head = (lane < (int)k) && (same_smaller == 0);
    u64 hb = __ballot(head);
    if (lane < (int)k) pairs[lo + rank] = v;
    if (lane == 0) bucketHeads[b] = (u32)__popcll(hb);
  } else if (lane == 0) {  // cold fallback
    for (u32 i = lo + 1; i < hi; i++) {
      u64 v = pairs[i];
      u32 j = i;
      while (j > lo && pairs[j - 1] > v) { pairs[j] = pairs[j - 1]; j--; }
      pairs[j] = v;
    }
    u32 u = 1;
    for (u32 i = lo + 1; i < hi; i++)
      u += ((u32)(pairs[i] >> 32) != (u32)(pairs[i - 1] >> 32)) ? 1u : 0u;
    bucketHeads[b] = u;
  }
}

// ---------- K2b: exclusive scan of bucket head counts -> segment bases (uint4 I/O) ----------
__global__ void k2b_scan(const u32* __restrict__ bucketHeads, u32* __restrict__ segBase,
                         u32* __restrict__ meta, u32* __restrict__ segStart, int n) {
  __shared__ u32 part[1024];
  int t = threadIdx.x;
  const uint4* h4 = (const uint4*)bucketHeads;
  uint4 v[16];
  u32 s = 0;
#pragma unroll
  for (int q = 0; q < 16; q++) {
    v[q] = h4[t * 16 + q];
    s += v[q].x + v[q].y + v[q].z + v[q].w;
  }
  part[t] = s;
  __syncthreads();
  for (int d = 1; d < 1024; d <<= 1) {
    u32 x = (t >= d) ? part[t - d] : 0u;
    __syncthreads();
    part[t] += x;
    __syncthreads();
  }
  u32 run = part[t] - s;
  uint4* sb4 = (uint4*)segBase;
#pragma unroll
  for (int q = 0; q < 16; q++) {
    uint4 o;
    o.x = run; run += v[q].x;
    o.y = run; run += v[q].y;
    o.z = run; run += v[q].z;
    o.w = run; run += v[q].w;
    sb4[t * 16 + q] = o;
  }
  if (t == 1023) {
    segBase[NBUCK] = run;
    meta[0] = run;            // numSeg
    meta[1] = 0u;             // multi-cluster counter
    segStart[run] = (u32)n;   // sentinel
  }
}

// ---------- K5: wave-per-bucket assignment + counts + coord means ----------
__global__ __launch_bounds__(256) void k5_assign(
    const u64* __restrict__ pairs, const u32* __restrict__ off,
    const u32* __restrict__ segBase, const float* __restrict__ coord,
    u32* __restrict__ segStart, u32* __restrict__ cluster,
    float* __restrict__ out_grid, float* __restrict__ out_batch,
    float* __restrict__ out_coord, float* __restrict__ out_counts,
    u32* __restrict__ meta, u32* __restrict__ multiList) {
  int b = (blockIdx.x * blockDim.x + threadIdx.x) >> 6;
  int lane = threadIdx.x & 63;
  if (b >= NBUCK) return;
  u32 lo = off[b], hi = off[b + 1];
  u32 k = hi - lo;
  if (k == 0) return;
  if (k <= 64) {
    bool inb = lane < (int)k;
    u64 v = inb ? pairs[lo + lane] : ~0ull;
    u32 mykey = (u32)(v >> 32);
    u32 idx = (u32)(v & 0xFFFFFFFFu);
    float cx = 0.f, cy = 0.f, cz = 0.f;
    if (inb) {
      cx = coord[(size_t)idx * 3 + 0];
      cy = coord[(size_t)idx * 3 + 1];
      cz = coord[(size_t)idx * 3 + 2];
    }
    u64 pv = __shfl_up(v, 1, 64);
    bool head = inb && (lane == 0 || (u32)(pv >> 32) != mykey);
    u64 hb = __ballot(head);
    u64 above = (lane < 63) ? (hb >> (lane + 1)) : 0ull;
#pragma unroll
    for (int d = 1; d < 64; d <<= 1) {
      float ox = __shfl_down(cx, d, 64);
      float oy = __shfl_down(cy, d, 64);
      float oz = __shfl_down(cz, d, 64);
      bool ok = (lane + d < 64) && ((above & ((1ull << d) - 1ull)) == 0ull);
      if (ok) { cx += ox; cy += oy; cz += oz; }
    }
    if (inb) {
      u32 seg = segBase[b] + (u32)__popcll(hb << (63 - lane)) - 1u;
      u32 cnt = above ? (u32)__builtin_ctzll(above) + 1u : (k - (u32)lane);
      bool multi_run = head ? (cnt > 1u) : true;
      cluster[idx] = seg | (multi_run ? 0x80000000u : 0u);
      if (head) {
        segStart[seg] = lo + (u32)lane;
        out_grid[(size_t)seg * 3 + 0] = (float)(mykey & 0x3FFu);
        out_grid[(size_t)seg * 3 + 1] = (float)((mykey >> 10) & 0x3FFu);
        out_grid[(size_t)seg * 3 + 2] = (float)((mykey >> 20) & 0x3FFu);
        out_batch[seg] = (float)(mykey >> 30);
        float fc = (float)cnt;
        out_counts[seg] = fc;
        out_coord[(size_t)seg * 3 + 0] = cx / fc;
        out_coord[(size_t)seg * 3 + 1] = cy / fc;
        out_coord[(size_t)seg * 3 + 2] = cz / fc;
        if (cnt > 1u) {
          u32 slot = atomicAdd(&meta[1], 1u);
          multiList[slot] = seg;
        }
      }
    }
  } else if (lane == 0) {  // cold fallback
    u32 seg = segBase[b];
    u32 p = lo;
    while (p < hi) {
      u32 kk = (u32)(pairs[p] >> 32);
      u32 q = p;
      float sx = 0.f, sy = 0.f, sz = 0.f;
      while (q < hi && (u32)(pairs[q] >> 32) == kk) {
        u32 idx = (u32)(pairs[q] & 0xFFFFFFFFu);
        sx += coord[(size_t)idx * 3 + 0];
        sy += coord[(size_t)idx * 3 + 1];
        sz += coord[(size_t)idx * 3 + 2];
        q++;
      }
      u32 cnt = q - p;
      u32 multi = (cnt > 1u) ? 0x80000000u : 0u;
      for (u32 e = p; e < q; e++) cluster[(u32)(pairs[e] & 0xFFFFFFFFu)] = seg | multi;
      segStart[seg] = p;
      out_grid[(size_t)seg * 3 + 0] = (float)(kk & 0x3FFu);
      out_grid[(size_t)seg * 3 + 1] = (float)((kk >> 10) & 0x3FFu);
      out_grid[(size_t)seg * 3 + 2] = (float)((kk >> 20) & 0x3FFu);
      out_batch[seg] = (float)(kk >> 30);
      float fc = (float)cnt;
      out_counts[seg] = fc;
      out_coord[(size_t)seg * 3 + 0] = sx / fc;
      out_coord[(size_t)seg * 3 + 1] = sy / fc;
      out_coord[(size_t)seg * 3 + 2] = sz / fc;
      if (cnt > 1u) {
        u32 slot = atomicAdd(&meta[1], 1u);
        multiList[slot] = seg;
      }
      seg++;
      p = q;
    }
  }
}

// ---------- K6: MFMA bf16 GEMM, no LDS. One wave = 16 points x 128 channels. ----------
// A frag (feat): row = lane&15, k = 8*(lane>>4)+i (contiguous 8, direct global load).
// B frag (W^T):  col = lane&15, k = 8*(lane>>4)+i  -> read W[c][k] row-major.
// C/D: col = lane&15, row = 4*(lane>>4)+reg (m89-verified).
__global__ __launch_bounds__(256) void k6_gemm(
    const float* __restrict__ feat, const float* __restrict__ weight,
    const float* __restrict__ bias, const u32* __restrict__ cluster,
    float* __restrict__ out_feat, int n) {
  const int lane = threadIdx.x & 63;
  const int wid = threadIdx.x >> 6;
  const int col = lane & 15;
  const int h = lane >> 4;

  // preload W fragments: wf[g][t] covers channels g*16..+15, k in [32t,32t+32)
  bf16x8 wf[8][2];
#pragma unroll
  for (int g = 0; g < 8; g++) {
    const float* wr = weight + (size_t)(g * 16 + col) * C_IN;
#pragma unroll
    for (int t = 0; t < 2; t++) {
      float4 a = *(const float4*)(wr + t * 32 + h * 8);
      float4 b = *(const float4*)(wr + t * 32 + h * 8 + 4);
      wf[g][t] = cvt8(a, b);
    }
  }
  float breg[8];
#pragma unroll
  for (int g = 0; g < 8; g++) breg[g] = bias[g * 16 + col];

  const int ntile = (n + 15) >> 4;
  for (int t = blockIdx.x * 4 + wid; t < ntile; t += gridDim.x * 4) {
    const int base = t << 4;
    int p = base + col;
    if (p >= n) p = n - 1;  // clamp; OOB rows are never stored
    const float* fr = feat + (size_t)p * C_IN;
    float4 a0 = *(const float4*)(fr + h * 8);
    float4 a1 = *(const float4*)(fr + h * 8 + 4);
    float4 a2 = *(const float4*)(fr + 32 + h * 8);
    float4 a3 = *(const float4*)(fr + 32 + h * 8 + 4);
    bf16x8 af0 = cvt8(a0, a1);
    bf16x8 af1 = cvt8(a2, a3);
    u32 cl[4];
#pragma unroll
    for (int i = 0; i < 4; i++) {
      int pp = base + 4 * h + i;
      cl[i] = (pp < n) ? cluster[pp] : 0x80000000u;
    }
#pragma unroll
    for (int g = 0; g < 8; g++) {
      f32x4 acc = {0.f, 0.f, 0.f, 0.f};
      acc = __builtin_amdgcn_mfma_f32_16x16x32_bf16(af0, wf[g][0], acc, 0, 0, 0);
      acc = __builtin_amdgcn_mfma_f32_16x16x32_bf16(af1, wf[g][1], acc, 0, 0, 0);
#pragma unroll
      for (int i = 0; i < 4; i++) {
        if (!(cl[i] & 0x80000000u))
          out_feat[(size_t)cl[i] * C_OUT + g * 16 + col] = acc[i] + breg[g];
      }
    }
  }
}

// ---------- K7t: zero the invalid tail rows ----------
__global__ void k7_tail(const u32* __restrict__ meta, float* __restrict__ out_feat,
                        float* __restrict__ out_coord, float* __restrict__ out_grid,
                        float* __restrict__ out_batch, float* __restrict__ out_counts, int n) {
  int t = blockIdx.x * blockDim.x + threadIdx.x;
  if (t >= n) return;
  if ((u32)t < meta[0]) return;
  out_counts[t] = 0.f;
  out_batch[t] = 0.f;
  out_coord[(size_t)t * 3 + 0] = 0.f;
  out_coord[(size_t)t * 3 + 1] = 0.f;
  out_coord[(size_t)t * 3 + 2] = 0.f;
  out_grid[(size_t)t * 3 + 0] = 0.f;
  out_grid[(size_t)t * 3 + 1] = 0.f;
  out_grid[(size_t)t * 3 + 2] = 0.f;
  float4 z = {0.f, 0.f, 0.f, 0.f};
  float4* row = (float4*)(out_feat + (size_t)t * C_OUT);
#pragma unroll
  for (int q = 0; q < 32; q++) row[q] = z;
}

// ---------- K8: multi-point clusters — parallel matmul + max (1 block/cluster) ----------
__global__ __launch_bounds__(128) void k8_multi(
    const u64* __restrict__ pairs, const u32* __restrict__ segStart,
    const u32* __restrict__ meta, const u32* __restrict__ multiList,
    const float* __restrict__ feat, const float* __restrict__ weight,
    const float* __restrict__ bias, float* __restrict__ out_feat) {
  __shared__ float ldsF[C_IN];
  const int c = threadIdx.x;
  float wreg[C_IN];
  const float4* wrow = (const float4*)(weight + (size_t)c * C_IN);
#pragma unroll
  for (int q = 0; q < 16; q++) {
    float4 v = wrow[q];
    wreg[4 * q] = v.x; wreg[4 * q + 1] = v.y; wreg[4 * q + 2] = v.z; wreg[4 * q + 3] = v.w;
  }
  const float bc = bias[c];
  const u32 nm = meta[1];
  for (u32 m = blockIdx.x; m < nm; m += gridDim.x) {
    u32 seg = multiList[m];
    u32 st = segStart[seg], en = segStart[seg + 1];
    float mx = -3.4e38f;
    for (u32 e = st; e < en; e++) {
      u32 idx = (u32)(pairs[e] & 0xFFFFFFFFu);
      __syncthreads();
      if (c < 16) ((float4*)ldsF)[c] = ((const float4*)(feat + (size_t)idx * C_IN))[c];
      __syncthreads();
      float d = bc;
#pragma unroll
      for (int q = 0; q < 16; q++) {
        float4 v = ((const float4*)ldsF)[q];
        d = fmaf(v.x, wreg[4 * q], d);
        d = fmaf(v.y, wreg[4 * q + 1], d);
        d = fmaf(v.z, wreg[4 * q + 2], d);
        d = fmaf(v.w, wreg[4 * q + 3], d);
      }
      mx = fmaxf(mx, d);
    }
    out_feat[(size_t)seg * C_OUT + c] = mx;
  }
}

extern "C" void kernel_launch(void* const* d_in, const int* in_sizes, int n_in,
                              void* d_out, int out_size, void* d_ws, size_t ws_size,
                              hipStream_t stream) {
  const float* feat = (const float*)d_in[0];
  const float* coord = (const float*)d_in[1];
  const float* weight = (const float*)d_in[2];
  const float* bias = (const float*)d_in[3];
  const int* grid = (const int*)d_in[4];
  const int* batch = (const int*)d_in[5];
  const int* stride = (const int*)d_in[6];
  const int n = in_sizes[0] / C_IN;

  float* out_feat = (float*)d_out;
  float* out_coord = out_feat + (size_t)n * C_OUT;
  float* out_grid = out_coord + (size_t)n * 3;
  float* out_batch = out_grid + (size_t)n * 3;
  float* out_counts = out_batch + n;

  u32* W = (u32*)d_ws;
  u32* hist = W;                     // 65536
  u32* cursor = W + 65536;           // 65536 (reused as bucketHeads after k3)
  u32* off = W + 131072;             // 65537
  u32* segBase = W + 196864;         // 65537
  u32* meta = W + 262464;            // [0]=numSeg [1]=numMulti
  u32* multiList = W + 262528;       // 65536
  u32* keys = W + 328192;            // n
  u32* cluster = keys + n;           // n
  u32* segStart = cluster + n;       // n+1
  size_t pe = 328192 + 3 * (size_t)n + 2;
  pe &= ~(size_t)1;                  // 8-byte align for u64
  u64* pairs = (u64*)(W + pe);       // n
  u32* bucketHeads = cursor;         // alias: cursor dead after k3

  int nb = (n + 255) / 256;
  k0_zero<<<NBUCK / 4 / 256, 256, 0, stream>>>((uint4*)hist);
  k1_keys<<<nb, 256, 0, stream>>>(grid, batch, stride, n, keys, hist);
  k2_scan<<<1, 1024, 0, stream>>>(hist, off, cursor);
  k3_scatter<<<nb, 256, 0, stream>>>(keys, cursor, pairs, n);
  k4_sort<<<NBUCK / 4, 256, 0, stream>>>(pairs, off, bucketHeads);
  k2b_scan<<<1, 1024, 0, stream>>>(bucketHeads, segBase, meta, segStart, n);
  k5_assign<<<NBUCK / 4, 256, 0, stream>>>(pairs, off, segBase, coord, segStart, cluster,
                                           out_grid, out_batch, out_coord, out_counts,
                                           meta, multiList);
  k6_gemm<<<2048, 256, 0, stream>>>(feat, weight, bias, cluster, out_feat, n);
  k7_tail<<<nb, 256, 0, stream>>>(meta, out_feat, out_coord, out_grid, out_batch, out_counts, n);
  k8_multi<<<256, 128, 0, stream>>>(pairs, segStart, meta, multiList, feat, weight, bias, out_feat);
}

// Round 9
// 208.625 us; speedup vs baseline: 1.4861x; 1.3021x over previous
//
#include <hip/hip_runtime.h>
#include <stdint.h>

#define C_IN 64
#define C_OUT 128
#define NBUCK 16384

typedef unsigned int u32;
typedef unsigned long long u64;
typedef __attribute__((ext_vector_type(8))) short bf16x8;
typedef __attribute__((ext_vector_type(4))) float f32x4;

__device__ __forceinline__ unsigned short f2bf(float f) {
  u32 x = __float_as_uint(f);
  u32 r = x + 0x7FFFu + ((x >> 16) & 1u);  // round-to-nearest-even
  return (unsigned short)(r >> 16);
}
__device__ __forceinline__ bf16x8 cvt8(float4 a, float4 b) {
  bf16x8 r;
  r[0] = (short)f2bf(a.x); r[1] = (short)f2bf(a.y);
  r[2] = (short)f2bf(a.z); r[3] = (short)f2bf(a.w);
  r[4] = (short)f2bf(b.x); r[5] = (short)f2bf(b.y);
  r[6] = (short)f2bf(b.z); r[7] = (short)f2bf(b.w);
  return r;
}
// order-preserving compacted bucket: (b, gz, gy>>6). Valid while g<512 (stride>=2).
__device__ __forceinline__ u32 bucket_of(u32 key) {
  return ((key >> 30) << 12) | (((key >> 20) & 0x1FFu) << 3) | ((key >> 16) & 7u);
}

// ---------- K0: zero the bucket histogram ----------
__global__ void k0_zero(uint4* __restrict__ hist4) {
  int i = blockIdx.x * blockDim.x + threadIdx.x;
  hist4[i] = make_uint4(0u, 0u, 0u, 0u);
}

// ---------- K1: compute compressed keys + bucket histogram ----------
__global__ void k1_keys(const int* __restrict__ grid, const int* __restrict__ batch,
                        const int* __restrict__ stride, int n,
                        u32* __restrict__ keys, u32* __restrict__ hist) {
  int i = blockIdx.x * blockDim.x + threadIdx.x;
  if (i >= n) return;
  int s = stride[0];
  u32 gx, gy, gz;
  if (s == 2) {
    gx = ((u32)grid[3 * i]) >> 1;
    gy = ((u32)grid[3 * i + 1]) >> 1;
    gz = ((u32)grid[3 * i + 2]) >> 1;
  } else {
    gx = (u32)(grid[3 * i] / s);
    gy = (u32)(grid[3 * i + 1] / s);
    gz = (u32)(grid[3 * i + 2] / s);
  }
  u32 b = (u32)batch[i];
  u32 key = (b << 30) | (gz << 20) | (gy << 10) | gx;
  keys[i] = key;
  atomicAdd(&hist[bucket_of(key)], 1u);
}

// ---------- K2: exclusive scan of 16384 bucket counts (1 block, uint4 I/O) ----------
__global__ void k2_scan(const u32* __restrict__ hist, u32* __restrict__ off,
                        u32* __restrict__ cursor) {
  __shared__ u32 part[1024];
  int t = threadIdx.x;
  const uint4* h4 = (const uint4*)hist;
  uint4 v[4];
  u32 s = 0;
#pragma unroll
  for (int q = 0; q < 4; q++) {
    v[q] = h4[t * 4 + q];
    s += v[q].x + v[q].y + v[q].z + v[q].w;
  }
  part[t] = s;
  __syncthreads();
  for (int d = 1; d < 1024; d <<= 1) {
    u32 x = (t >= d) ? part[t - d] : 0u;
    __syncthreads();
    part[t] += x;
    __syncthreads();
  }
  u32 run = part[t] - s;
  uint4* off4 = (uint4*)off;
  uint4* cur4 = (uint4*)cursor;
#pragma unroll
  for (int q = 0; q < 4; q++) {
    uint4 o;
    o.x = run; run += v[q].x;
    o.y = run; run += v[q].y;
    o.z = run; run += v[q].z;
    o.w = run; run += v[q].w;
    off4[t * 4 + q] = o;
    cur4[t * 4 + q] = o;
  }
  if (t == 1023) off[NBUCK] = run;  // == n
}

// ---------- K3: scatter (key,idx) pairs into buckets ----------
__global__ void k3_scatter(const u32* __restrict__ keys, u32* __restrict__ cursor,
                           u64* __restrict__ pairs, int n) {
  int i = blockIdx.x * blockDim.x + threadIdx.x;
  if (i >= n) return;
  u32 key = keys[i];
  u32 pos = atomicAdd(&cursor[bucket_of(key)], 1u);
  pairs[pos] = ((u64)key << 32) | (u32)i;
}

// ---------- K4: per-bucket rank sort + unique-key count, one WAVE per bucket ----------
__global__ __launch_bounds__(256) void k4_sort(u64* __restrict__ pairs,
                                               const u32* __restrict__ off,
                                               u32* __restrict__ bucketHeads) {
  int b = (blockIdx.x * blockDim.x + threadIdx.x) >> 6;
  int lane = threadIdx.x & 63;
  if (b >= NBUCK) return;
  u32 lo = off[b], hi = off[b + 1];
  u32 k = hi - lo;
  if (k == 0) { if (lane == 0) bucketHeads[b] = 0u; return; }
  if (k == 1) { if (lane == 0) bucketHeads[b] = 1u; return; }
  if (k <= 64) {
    u64 v = (lane < (int)k) ? pairs[lo + lane] : ~0ull;
    u32 mykey = (u32)(v >> 32);
    int rank = 0, same_smaller = 0;
    for (u32 j = 0; j < k; j++) {
      u64 o = __shfl(v, (int)j, 64);
      bool lt = o < v;
      rank += lt ? 1 : 0;
      same_smaller += (lt && ((u32)(o >> 32) == mykey)) ? 1 : 0;
    }
    bool head = (lane < (int)k) && (same_smaller == 0);
    u64 hb = __ballot(head);
    if (lane < (int)k) pairs[lo + rank] = v;
    if (lane == 0) bucketHeads[b] = (u32)__popcll(hb);
  } else if (lane == 0) {  // cold fallback
    for (u32 i = lo + 1; i < hi; i++) {
      u64 v = pairs[i];
      u32 j = i;
      while (j > lo && pairs[j - 1] > v) { pairs[j] = pairs[j - 1]; j--; }
      pairs[j] = v;
    }
    u32 u = 1;
    for (u32 i = lo + 1; i < hi; i++)
      u += ((u32)(pairs[i] >> 32) != (u32)(pairs[i - 1] >> 32)) ? 1u : 0u;
    bucketHeads[b] = u;
  }
}

// ---------- K2b: exclusive scan of bucket head counts -> segment bases ----------
__global__ void k2b_scan(const u32* __restrict__ bucketHeads, u32* __restrict__ segBase,
                         u32* __restrict__ meta, u32* __restrict__ segStart, int n) {
  __shared__ u32 part[1024];
  int t = threadIdx.x;
  const uint4* h4 = (const uint4*)bucketHeads;
  uint4 v[4];
  u32 s = 0;
#pragma unroll
  for (int q = 0; q < 4; q++) {
    v[q] = h4[t * 4 + q];
    s += v[q].x + v[q].y + v[q].z + v[q].w;
  }
  part[t] = s;
  __syncthreads();
  for (int d = 1; d < 1024; d <<= 1) {
    u32 x = (t >= d) ? part[t - d] : 0u;
    __syncthreads();
    part[t] += x;
    __syncthreads();
  }
  u32 run = part[t] - s;
  uint4* sb4 = (uint4*)segBase;
#pragma unroll
  for (int q = 0; q < 4; q++) {
    uint4 o;
    o.x = run; run += v[q].x;
    o.y = run; run += v[q].y;
    o.z = run; run += v[q].z;
    o.w = run; run += v[q].w;
    sb4[t * 4 + q] = o;
  }
  if (t == 1023) {
    segBase[NBUCK] = run;
    meta[0] = run;            // numSeg
    meta[1] = 0u;             // multi-cluster counter
    segStart[run] = (u32)n;   // sentinel
  }
}

// ---------- K5: wave-per-bucket assignment + counts + coord means ----------
__global__ __launch_bounds__(256) void k5_assign(
    const u64* __restrict__ pairs, const u32* __restrict__ off,
    const u32* __restrict__ segBase, const float* __restrict__ coord,
    u32* __restrict__ segStart, u32* __restrict__ cluster,
    float* __restrict__ out_grid, float* __restrict__ out_batch,
    float* __restrict__ out_coord, float* __restrict__ out_counts,
    u32* __restrict__ meta, u32* __restrict__ multiList) {
  int b = (blockIdx.x * blockDim.x + threadIdx.x) >> 6;
  int lane = threadIdx.x & 63;
  if (b >= NBUCK) return;
  u32 lo = off[b], hi = off[b + 1];
  u32 k = hi - lo;
  if (k == 0) return;
  if (k <= 64) {
    bool inb = lane < (int)k;
    u64 v = inb ? pairs[lo + lane] : ~0ull;
    u32 mykey = (u32)(v >> 32);
    u32 idx = (u32)(v & 0xFFFFFFFFu);
    float cx = 0.f, cy = 0.f, cz = 0.f;
    if (inb) {
      cx = coord[(size_t)idx * 3 + 0];
      cy = coord[(size_t)idx * 3 + 1];
      cz = coord[(size_t)idx * 3 + 2];
    }
    u64 pv = __shfl_up(v, 1, 64);
    bool head = inb && (lane == 0 || (u32)(pv >> 32) != mykey);
    u64 hb = __ballot(head);
    u64 above = (lane < 63) ? (hb >> (lane + 1)) : 0ull;
#pragma unroll
    for (int d = 1; d < 64; d <<= 1) {
      float ox = __shfl_down(cx, d, 64);
      float oy = __shfl_down(cy, d, 64);
      float oz = __shfl_down(cz, d, 64);
      bool ok = (lane + d < 64) && ((above & ((1ull << d) - 1ull)) == 0ull);
      if (ok) { cx += ox; cy += oy; cz += oz; }
    }
    if (inb) {
      u32 seg = segBase[b] + (u32)__popcll(hb << (63 - lane)) - 1u;
      u32 cnt = above ? (u32)__builtin_ctzll(above) + 1u : (k - (u32)lane);
      bool multi_run = head ? (cnt > 1u) : true;
      cluster[idx] = seg | (multi_run ? 0x80000000u : 0u);
      if (head) {
        segStart[seg] = lo + (u32)lane;
        out_grid[(size_t)seg * 3 + 0] = (float)(mykey & 0x3FFu);
        out_grid[(size_t)seg * 3 + 1] = (float)((mykey >> 10) & 0x3FFu);
        out_grid[(size_t)seg * 3 + 2] = (float)((mykey >> 20) & 0x3FFu);
        out_batch[seg] = (float)(mykey >> 30);
        float fc = (float)cnt;
        out_counts[seg] = fc;
        out_coord[(size_t)seg * 3 + 0] = cx / fc;
        out_coord[(size_t)seg * 3 + 1] = cy / fc;
        out_coord[(size_t)seg * 3 + 2] = cz / fc;
        if (cnt > 1u) {
          u32 slot = atomicAdd(&meta[1], 1u);
          multiList[slot] = seg;
        }
      }
    }
  } else if (lane == 0) {  // cold fallback
    u32 seg = segBase[b];
    u32 p = lo;
    while (p < hi) {
      u32 kk = (u32)(pairs[p] >> 32);
      u32 q = p;
      float sx = 0.f, sy = 0.f, sz = 0.f;
      while (q < hi && (u32)(pairs[q] >> 32) == kk) {
        u32 idx = (u32)(pairs[q] & 0xFFFFFFFFu);
        sx += coord[(size_t)idx * 3 + 0];
        sy += coord[(size_t)idx * 3 + 1];
        sz += coord[(size_t)idx * 3 + 2];
        q++;
      }
      u32 cnt = q - p;
      u32 multi = (cnt > 1u) ? 0x80000000u : 0u;
      for (u32 e = p; e < q; e++) cluster[(u32)(pairs[e] & 0xFFFFFFFFu)] = seg | multi;
      segStart[seg] = p;
      out_grid[(size_t)seg * 3 + 0] = (float)(kk & 0x3FFu);
      out_grid[(size_t)seg * 3 + 1] = (float)((kk >> 10) & 0x3FFu);
      out_grid[(size_t)seg * 3 + 2] = (float)((kk >> 20) & 0x3FFu);
      out_batch[seg] = (float)(kk >> 30);
      float fc = (float)cnt;
      out_counts[seg] = fc;
      out_coord[(size_t)seg * 3 + 0] = sx / fc;
      out_coord[(size_t)seg * 3 + 1] = sy / fc;
      out_coord[(size_t)seg * 3 + 2] = sz / fc;
      if (cnt > 1u) {
        u32 slot = atomicAdd(&meta[1], 1u);
        multiList[slot] = seg;
      }
      seg++;
      p = q;
    }
  }
}

// ---------- K6: MFMA bf16 GEMM, no LDS, 64-point macro-tiles for MLP ----------
__global__ __launch_bounds__(256) void k6_gemm(
    const float* __restrict__ feat, const float* __restrict__ weight,
    const float* __restrict__ bias, const u32* __restrict__ cluster,
    float* __restrict__ out_feat, int n) {
  const int lane = threadIdx.x & 63;
  const int wid = threadIdx.x >> 6;
  const int col = lane & 15;
  const int h = lane >> 4;

  bf16x8 wf[8][2];
#pragma unroll
  for (int g = 0; g < 8; g++) {
    const float* wr = weight + (size_t)(g * 16 + col) * C_IN;
#pragma unroll
    for (int t = 0; t < 2; t++) {
      float4 a = *(const float4*)(wr + t * 32 + h * 8);
      float4 b = *(const float4*)(wr + t * 32 + h * 8 + 4);
      wf[g][t] = cvt8(a, b);
    }
  }
  float breg[8];
#pragma unroll
  for (int g = 0; g < 8; g++) breg[g] = bias[g * 16 + col];

  const int nmt = (n + 63) >> 6;
  for (int t = blockIdx.x * 4 + wid; t < nmt; t += gridDim.x * 4) {
    const int base = t << 6;
    float4 raw[4][4];
    u32 cme;
    if (base + 64 <= n) {  // fast path: 16 loads + 1 cluster load all in flight
#pragma unroll
      for (int s = 0; s < 4; s++) {
        const float* fr = feat + (size_t)(base + s * 16 + col) * C_IN;
        raw[s][0] = *(const float4*)(fr + h * 8);
        raw[s][1] = *(const float4*)(fr + h * 8 + 4);
        raw[s][2] = *(const float4*)(fr + 32 + h * 8);
        raw[s][3] = *(const float4*)(fr + 32 + h * 8 + 4);
      }
      cme = cluster[base + lane];
    } else {
#pragma unroll
      for (int s = 0; s < 4; s++) {
        int p = base + s * 16 + col;
        if (p >= n) p = n - 1;
        const float* fr = feat + (size_t)p * C_IN;
        raw[s][0] = *(const float4*)(fr + h * 8);
        raw[s][1] = *(const float4*)(fr + h * 8 + 4);
        raw[s][2] = *(const float4*)(fr + 32 + h * 8);
        raw[s][3] = *(const float4*)(fr + 32 + h * 8 + 4);
      }
      cme = (base + lane < n) ? cluster[base + lane] : 0x80000000u;
    }
#pragma unroll
    for (int s = 0; s < 4; s++) {
      bf16x8 af0 = cvt8(raw[s][0], raw[s][1]);
      bf16x8 af1 = cvt8(raw[s][2], raw[s][3]);
      u32 cl[4];
#pragma unroll
      for (int i = 0; i < 4; i++) cl[i] = __shfl(cme, s * 16 + 4 * h + i, 64);
#pragma unroll
      for (int g = 0; g < 8; g++) {
        f32x4 acc = {0.f, 0.f, 0.f, 0.f};
        acc = __builtin_amdgcn_mfma_f32_16x16x32_bf16(af0, wf[g][0], acc, 0, 0, 0);
        acc = __builtin_amdgcn_mfma_f32_16x16x32_bf16(af1, wf[g][1], acc, 0, 0, 0);
#pragma unroll
        for (int i = 0; i < 4; i++) {
          if (!(cl[i] & 0x80000000u))
            __builtin_nontemporal_store(
                acc[i] + breg[g], &out_feat[(size_t)cl[i] * C_OUT + g * 16 + col]);
        }
      }
    }
  }
}

// ---------- K7t: zero the invalid tail rows ----------
__global__ void k7_tail(const u32* __restrict__ meta, float* __restrict__ out_feat,
                        float* __restrict__ out_coord, float* __restrict__ out_grid,
                        float* __restrict__ out_batch, float* __restrict__ out_counts, int n) {
  int t = blockIdx.x * blockDim.x + threadIdx.x;
  if (t >= n) return;
  if ((u32)t < meta[0]) return;
  out_counts[t] = 0.f;
  out_batch[t] = 0.f;
  out_coord[(size_t)t * 3 + 0] = 0.f;
  out_coord[(size_t)t * 3 + 1] = 0.f;
  out_coord[(size_t)t * 3 + 2] = 0.f;
  out_grid[(size_t)t * 3 + 0] = 0.f;
  out_grid[(size_t)t * 3 + 1] = 0.f;
  out_grid[(size_t)t * 3 + 2] = 0.f;
  float4 z = {0.f, 0.f, 0.f, 0.f};
  float4* row = (float4*)(out_feat + (size_t)t * C_OUT);
#pragma unroll
  for (int q = 0; q < 32; q++) row[q] = z;
}

// ---------- K8: multi-point clusters — parallel matmul + max (1 block/cluster) ----------
__global__ __launch_bounds__(128) void k8_multi(
    const u64* __restrict__ pairs, const u32* __restrict__ segStart,
    const u32* __restrict__ meta, const u32* __restrict__ multiList,
    const float* __restrict__ feat, const float* __restrict__ weight,
    const float* __restrict__ bias, float* __restrict__ out_feat) {
  __shared__ float ldsF[C_IN];
  const int c = threadIdx.x;
  float wreg[C_IN];
  const float4* wrow = (const float4*)(weight + (size_t)c * C_IN);
#pragma unroll
  for (int q = 0; q < 16; q++) {
    float4 v = wrow[q];
    wreg[4 * q] = v.x; wreg[4 * q + 1] = v.y; wreg[4 * q + 2] = v.z; wreg[4 * q + 3] = v.w;
  }
  const float bc = bias[c];
  const u32 nm = meta[1];
  for (u32 m = blockIdx.x; m < nm; m += gridDim.x) {
    u32 seg = multiList[m];
    u32 st = segStart[seg], en = segStart[seg + 1];
    float mx = -3.4e38f;
    for (u32 e = st; e < en; e++) {
      u32 idx = (u32)(pairs[e] & 0xFFFFFFFFu);
      __syncthreads();
      if (c < 16) ((float4*)ldsF)[c] = ((const float4*)(feat + (size_t)idx * C_IN))[c];
      __syncthreads();
      float d = bc;
#pragma unroll
      for (int q = 0; q < 16; q++) {
        float4 v = ((const float4*)ldsF)[q];
        d = fmaf(v.x, wreg[4 * q], d);
        d = fmaf(v.y, wreg[4 * q + 1], d);
        d = fmaf(v.z, wreg[4 * q + 2], d);
        d = fmaf(v.w, wreg[4 * q + 3], d);
      }
      mx = fmaxf(mx, d);
    }
    out_feat[(size_t)seg * C_OUT + c] = mx;
  }
}

extern "C" void kernel_launch(void* const* d_in, const int* in_sizes, int n_in,
                              void* d_out, int out_size, void* d_ws, size_t ws_size,
                              hipStream_t stream) {
  const float* feat = (const float*)d_in[0];
  const float* coord = (const float*)d_in[1];
  const float* weight = (const float*)d_in[2];
  const float* bias = (const float*)d_in[3];
  const int* grid = (const int*)d_in[4];
  const int* batch = (const int*)d_in[5];
  const int* stride = (const int*)d_in[6];
  const int n = in_sizes[0] / C_IN;

  float* out_feat = (float*)d_out;
  float* out_coord = out_feat + (size_t)n * C_OUT;
  float* out_grid = out_coord + (size_t)n * 3;
  float* out_batch = out_grid + (size_t)n * 3;
  float* out_counts = out_batch + n;

  u32* W = (u32*)d_ws;
  u32* hist = W;                     // 16384
  u32* cursor = W + 16384;           // 16384 (reused as bucketHeads after k3)
  u32* off = W + 32768;              // 16385 (reserve 16512)
  u32* segBase = W + 49280;          // 16385 (reserve 16512)
  u32* meta = W + 65792;             // 64
  u32* multiList = W + 65856;        // 65536
  u32* keys = W + 131392;            // n
  u32* cluster = keys + n;           // n
  u32* segStart = cluster + n;       // n+1
  size_t pe = 131392 + 3 * (size_t)n + 2;
  pe &= ~(size_t)1;                  // 8-byte align for u64
  u64* pairs = (u64*)(W + pe);       // n
  u32* bucketHeads = cursor;         // alias: cursor dead after k3

  int nb = (n + 255) / 256;
  k0_zero<<<NBUCK / 4 / 256, 256, 0, stream>>>((uint4*)hist);
  k1_keys<<<nb, 256, 0, stream>>>(grid, batch, stride, n, keys, hist);
  k2_scan<<<1, 1024, 0, stream>>>(hist, off, cursor);
  k3_scatter<<<nb, 256, 0, stream>>>(keys, cursor, pairs, n);
  k4_sort<<<NBUCK / 4, 256, 0, stream>>>(pairs, off, bucketHeads);
  k2b_scan<<<1, 1024, 0, stream>>>(bucketHeads, segBase, meta, segStart, n);
  k5_assign<<<NBUCK / 4, 256, 0, stream>>>(pairs, off, segBase, coord, segStart, cluster,
                                           out_grid, out_batch, out_coord, out_counts,
                                           meta, multiList);
  k6_gemm<<<2048, 256, 0, stream>>>(feat, weight, bias, cluster, out_feat, n);
  k7_tail<<<nb, 256, 0, stream>>>(meta, out_feat, out_coord, out_grid, out_batch, out_counts, n);
  k8_multi<<<256, 128, 0, stream>>>(pairs, segStart, meta, multiList, feat, weight, bias, out_feat);
}